// Round 2
// baseline (17490.820 us; speedup 1.0000x reference)
//
#include <hip/hip_runtime.h>
#include <cstdint>
#include <cstddef>

#define B_   32
#define SE_  256
#define HE_  512
#define HD_  1024
#define ED_  256
#define N_   8192
#define T_   20
#define KE_  1024
#define VE_  1024
#define MD_  256
#define EIN_ 768
#define G4_  4096
#define NEG_   (-10000000.0f)
#define MAXV_  (1000000000.0f)
#define EPS_   (1e-8f)
#define SPARSE_ 0.8f

// output offsets (floats)
#define O_IDS  (B_*T_*N_)            // 5242880
#define O_KEY  (O_IDS + B_*T_)       // 5243520
#define O_VAL  (O_KEY + B_*KE_)      // 5276288

__device__ __forceinline__ float sigf(float v) { return 1.0f / (1.0f + expf(-v)); }

// Bool-mask layout probe: harness may store bools as int32 (documented
// "integer -> const int*") or as packed bytes. All-true int32 word = 1;
// all-true byte word = 0x01010101 (> 0xFF).
__device__ __forceinline__ bool mask_is_b8(const void* p) {
    unsigned u = *(const unsigned*)p;
    return u > 0xFFu;
}
__device__ __forceinline__ bool mask_at(const void* p, int idx, bool b8) {
    return b8 ? (((const unsigned char*)p)[idx] != 0)
              : (((const int*)p)[idx] != 0);
}

// ---------------------------------------------------------------- init
__global__ __launch_bounds__(256) void k_init(
    const float* __restrict__ hidden, const float* __restrict__ cell,
    const float* __restrict__ enc, const void* __restrict__ encmask,
    float* __restrict__ h, float* __restrict__ c, float* __restrict__ x,
    float* __restrict__ lmask, float* __restrict__ sent, float* __restrict__ pad,
    float* __restrict__ key_run, float* __restrict__ val_sim)
{
    int idx = blockIdx.x * 256 + threadIdx.x;   // 0 .. 262143
    lmask[idx] = 0.0f;
    if (idx < B_ * HD_) {
        int b = idx >> 10, j = idx & 1023;
        int d = j >> 9, e = j & 511;
        h[idx] = hidden[((size_t)d * B_ + b) * HE_ + e];
        c[idx] = cell  [((size_t)d * B_ + b) * HE_ + e];
        key_run[idx] = -1e30f;
        val_sim[idx] = 0.0f;
    }
    if (idx < B_ * EIN_) x[idx] = 0.0f;
    if (idx < B_ * HE_) {
        int b = idx >> 9, e = idx & 511;
        sent[idx] = enc[(size_t)b * SE_ * HE_ + e];
    }
    if (idx < B_ * SE_) {
        bool b8 = mask_is_b8(encmask);
        pad[idx] = mask_at(encmask, idx, b8) ? 0.0f : -MAXV_;
    }
}

// ---------------------------------------------------------------- row norms
__global__ __launch_bounds__(256) void k_norms(
    const float* __restrict__ mem_k, const float* __restrict__ mem_v,
    float* __restrict__ normk, float* __restrict__ normv)
{
    int lane = threadIdx.x & 63;
    int wave = (blockIdx.x * 256 + threadIdx.x) >> 6;   // 0..1023
    for (int row = wave; row < 2 * B_ * KE_; row += 1024) {
        const float* base = (row < B_ * KE_) ? (mem_k + (size_t)row * MD_)
                                             : (mem_v + (size_t)(row - B_ * KE_) * MD_);
        float4 v = ((const float4*)base)[lane];   // MD_=256 -> 64 lanes x float4
        float s = v.x*v.x + v.y*v.y + v.z*v.z + v.w*v.w;
        for (int m = 32; m; m >>= 1) s += __shfl_xor(s, m, 64);
        if (lane == 0) {
            if (row < B_ * KE_) normk[row] = sqrtf(s);
            else                normv[row - B_ * KE_] = sqrtf(s);
        }
    }
}

// ---------------------------------------------------------------- rowmax of cos(mem_k, mem_v)
// grid (16 ktiles, 32 b), 256 threads = 16x16, tile 64k x 1024v, K=256 in chunks of 64
__global__ __launch_bounds__(256) void k_rowmax(
    const float* __restrict__ mem_k, const float* __restrict__ mem_v,
    const float* __restrict__ normk, const float* __restrict__ normv,
    float* __restrict__ rowmax)
{
    __shared__ __align__(16) float As[64 * 68];
    __shared__ __align__(16) float Bs[64 * 68];
    const int tid = threadIdx.x;
    const int tx = tid & 15, ty = tid >> 4;
    const int b = blockIdx.y;
    const int k0 = blockIdx.x * 64;

    float nk[4];
    #pragma unroll
    for (int i = 0; i < 4; ++i) nk[i] = normk[b * KE_ + k0 + ty * 4 + i];

    float rmax[4] = {-1e30f, -1e30f, -1e30f, -1e30f};

    for (int vc = 0; vc < 16; ++vc) {
        const int v0 = vc * 64;
        float acc[4][4];
        #pragma unroll
        for (int i = 0; i < 4; ++i)
            #pragma unroll
            for (int j = 0; j < 4; ++j) acc[i][j] = 0.0f;

        for (int kc = 0; kc < 4; ++kc) {
            __syncthreads();
            #pragma unroll
            for (int qi = 0; qi < 4; ++qi) {
                int lin = tid + qi * 256;           // 0..1023 quads
                int r = lin >> 4, qc = lin & 15;
                float4 av = *(const float4*)(mem_k + ((size_t)(b * KE_ + k0 + r)) * MD_ + kc * 64 + qc * 4);
                float4 bv = *(const float4*)(mem_v + ((size_t)(b * VE_ + v0 + r)) * MD_ + kc * 64 + qc * 4);
                *(float4*)&As[r * 68 + qc * 4] = av;
                *(float4*)&Bs[r * 68 + qc * 4] = bv;
            }
            __syncthreads();
            #pragma unroll
            for (int kq = 0; kq < 16; ++kq) {
                float4 a4[4], b4[4];
                #pragma unroll
                for (int i = 0; i < 4; ++i) a4[i] = *(const float4*)&As[(ty * 4 + i) * 68 + kq * 4];
                #pragma unroll
                for (int i = 0; i < 4; ++i) b4[i] = *(const float4*)&Bs[(tx * 4 + i) * 68 + kq * 4];
                #pragma unroll
                for (int i = 0; i < 4; ++i)
                    #pragma unroll
                    for (int j = 0; j < 4; ++j) {
                        acc[i][j] = fmaf(a4[i].x, b4[j].x, acc[i][j]);
                        acc[i][j] = fmaf(a4[i].y, b4[j].y, acc[i][j]);
                        acc[i][j] = fmaf(a4[i].z, b4[j].z, acc[i][j]);
                        acc[i][j] = fmaf(a4[i].w, b4[j].w, acc[i][j]);
                    }
            }
        }
        // epilogue: cos + row max
        #pragma unroll
        for (int j = 0; j < 4; ++j) {
            float nv = normv[b * VE_ + v0 + tx * 4 + j];
            #pragma unroll
            for (int i = 0; i < 4; ++i) {
                float cs = acc[i][j] / fmaxf(nk[i] * nv, EPS_);
                rmax[i] = fmaxf(rmax[i], cs);
            }
        }
    }
    __syncthreads();
    float* red = Bs;                                 // reuse
    #pragma unroll
    for (int i = 0; i < 4; ++i) red[(ty * 4 + i) * 16 + tx] = rmax[i];
    __syncthreads();
    if (tid < 64) {
        float m = red[tid * 16];
        #pragma unroll
        for (int k = 1; k < 16; ++k) m = fmaxf(m, red[tid * 16 + k]);
        rowmax[(size_t)b * KE_ + k0 + tid] = m;
    }
}

// ---------------------------------------------------------------- skinny GEMM: C[b,j] = X1[b,:]W1[j,:] (+X2W2) + biases (+mask) (opt relu)
// block: 16 j x 16 k-slices; grid.x = J/16
__global__ __launch_bounds__(256) void k_gemm(
    const float* __restrict__ X1, const float* __restrict__ W1, int K1,
    const float* __restrict__ X2, const float* __restrict__ W2, int K2,
    const float* __restrict__ bias1, const float* __restrict__ bias2,
    const float* __restrict__ addmask, int maskStride,
    float* __restrict__ out, long long outRowStride, int relu)
{
    const int tid = threadIdx.x;
    const int jj = tid >> 4, kg = tid & 15;
    const int j = blockIdx.x * 16 + jj;
    float acc[B_];
    #pragma unroll
    for (int b = 0; b < B_; ++b) acc[b] = 0.0f;

    {
        const float4* Wr = (const float4*)(W1 + (size_t)j * K1);
        const int nq = K1 >> 2;
        for (int q = kg; q < nq; q += 16) {
            float4 w4 = Wr[q];
            #pragma unroll
            for (int b = 0; b < B_; ++b) {
                float4 x4 = ((const float4*)(X1 + b * K1))[q];
                acc[b] = fmaf(w4.x, x4.x, acc[b]);
                acc[b] = fmaf(w4.y, x4.y, acc[b]);
                acc[b] = fmaf(w4.z, x4.z, acc[b]);
                acc[b] = fmaf(w4.w, x4.w, acc[b]);
            }
        }
    }
    if (X2) {
        const float4* Wr = (const float4*)(W2 + (size_t)j * K2);
        const int nq = K2 >> 2;
        for (int q = kg; q < nq; q += 16) {
            float4 w4 = Wr[q];
            #pragma unroll
            for (int b = 0; b < B_; ++b) {
                float4 x4 = ((const float4*)(X2 + b * K2))[q];
                acc[b] = fmaf(w4.x, x4.x, acc[b]);
                acc[b] = fmaf(w4.y, x4.y, acc[b]);
                acc[b] = fmaf(w4.z, x4.z, acc[b]);
                acc[b] = fmaf(w4.w, x4.w, acc[b]);
            }
        }
    }
    __shared__ float red[16][B_][16];
    #pragma unroll
    for (int b = 0; b < B_; ++b) red[jj][b][kg] = acc[b];
    __syncthreads();
    for (int o = tid; o < 16 * B_; o += 256) {
        int jjo = o >> 5, b = o & 31;
        float s = 0.0f;
        #pragma unroll
        for (int k = 0; k < 16; ++k) s += red[jjo][b][k];
        int jo = blockIdx.x * 16 + jjo;
        s += bias1[jo];
        if (bias2) s += bias2[jo];
        if (addmask) s += addmask[(size_t)b * maskStride + jo];
        if (relu) s = fmaxf(s, 0.0f);
        out[(size_t)b * outRowStride + jo] = s;
    }
}

// ---------------------------------------------------------------- LSTM pointwise
__global__ __launch_bounds__(256) void k_lstm(
    const float* __restrict__ g, float* __restrict__ h, float* __restrict__ c)
{
    int idx = blockIdx.x * 256 + threadIdx.x;       // 0..32767
    int b = idx >> 10, j = idx & 1023;
    const float* gb = g + (size_t)b * G4_;
    float gi = gb[j], gf = gb[HD_ + j], gg = gb[2 * HD_ + j], go = gb[3 * HD_ + j];
    float c1 = sigf(gf) * c[idx] + sigf(gi) * tanhf(gg);
    h[idx] = sigf(go) * tanhf(c1);
    c[idx] = c1;
}

// ---------------------------------------------------------------- argmax over logits (in d_out), update lmask, emit next_ids
__global__ __launch_bounds__(256) void k_argmax(
    float* __restrict__ d_out, int t, int* __restrict__ nidbuf, float* __restrict__ lmask)
{
    __shared__ float sv[256];
    __shared__ int   si[256];
    const int b = blockIdx.x, tid = threadIdx.x;
    const float* lg = d_out + ((size_t)b * T_ + t) * N_;
    float best = -1e38f; int bi = 0;
    for (int j = tid; j < N_; j += 256) {
        float v = lg[j];
        if (v > best) { best = v; bi = j; }
    }
    sv[tid] = best; si[tid] = bi;
    __syncthreads();
    for (int s = 128; s > 0; s >>= 1) {
        if (tid < s) {
            float v2 = sv[tid + s]; int i2 = si[tid + s];
            if (v2 > sv[tid] || (v2 == sv[tid] && i2 < si[tid])) { sv[tid] = v2; si[tid] = i2; }
        }
        __syncthreads();
    }
    if (tid == 0) {
        int nid = si[0];
        nidbuf[b] = nid;
        d_out[O_IDS + (size_t)b * T_ + t] = (float)nid;
        lmask[(size_t)b * N_ + nid] = NEG_;
        lmask[(size_t)b * N_] = 0.0f;   // EOS column reset AFTER nid set
    }
}

// ---------------------------------------------------------------- wave dot helper (row global x vec in LDS)
__device__ __forceinline__ float wave_dot(const float* __restrict__ row, const float* vl, int quads)
{
    int lane = threadIdx.x & 63;
    float s = 0.0f;
    for (int q = lane; q < quads; q += 64) {
        float4 a = ((const float4*)row)[q];
        float4 x = ((const float4*)vl)[q];
        s = fmaf(a.x, x.x, s); s = fmaf(a.y, x.y, s);
        s = fmaf(a.z, x.z, s); s = fmaf(a.w, x.w, s);
    }
    for (int m = 32; m; m >>= 1) s += __shfl_xor(s, m, 64);
    return s;
}

// ---------------------------------------------------------------- per-step tail: emb lookup, attention, x, mq, ksim
__global__ __launch_bounds__(256) void k_step2(
    const int* __restrict__ nidbuf, const float* __restrict__ emb,
    const float* __restrict__ dense_W, const float* __restrict__ dense_b,
    const float* __restrict__ enc, const float* __restrict__ pad,
    const float* __restrict__ sent,
    const float* __restrict__ read_W, const float* __restrict__ read_b,
    const float* __restrict__ mem_k, const float* __restrict__ normk,
    float* __restrict__ key_run, float* __restrict__ xg)
{
    __shared__ __align__(16) float x_l[EIN_];
    __shared__ __align__(16) float q_l[HE_];
    __shared__ __align__(16) float sc_l[SE_];
    __shared__ __align__(16) float w_l[SE_];
    __shared__ __align__(16) float mq_l[MD_];
    __shared__ float red[256];
    const int b = blockIdx.x, tid = threadIdx.x;
    const int wid = tid >> 6, lane = tid & 63;

    int nid = nidbuf[b];
    x_l[tid] = emb[(size_t)nid * ED_ + tid];
    __syncthreads();

    for (int j = wid; j < HE_; j += 4) {
        float v = wave_dot(dense_W + (size_t)j * ED_, x_l, ED_ / 4);
        if (lane == 0) q_l[j] = v + dense_b[j];
    }
    __syncthreads();

    for (int s = wid; s < SE_; s += 4) {
        float v = wave_dot(enc + ((size_t)b * SE_ + s) * HE_, q_l, HE_ / 4);
        if (lane == 0) sc_l[s] = v + pad[b * SE_ + s];
    }
    __syncthreads();

    float sv = sc_l[tid];
    red[tid] = sv; __syncthreads();
    for (int s = 128; s > 0; s >>= 1) { if (tid < s) red[tid] = fmaxf(red[tid], red[tid + s]); __syncthreads(); }
    float mx = red[0]; __syncthreads();
    float ev = expf(sv - mx);
    red[tid] = ev; __syncthreads();
    for (int s = 128; s > 0; s >>= 1) { if (tid < s) red[tid] += red[tid + s]; __syncthreads(); }
    float inv = 1.0f / red[0];
    w_l[tid] = ev * inv;
    __syncthreads();

    for (int ee = tid; ee < HE_; ee += 256) {
        float a = 0.0f;
        for (int s = 0; s < SE_; ++s) a = fmaf(w_l[s], enc[((size_t)b * SE_ + s) * HE_ + ee], a);
        float xv = sent[b * HE_ + ee] + a;
        x_l[ED_ + ee] = xv;
        xg[(size_t)b * EIN_ + ED_ + ee] = xv;
    }
    xg[(size_t)b * EIN_ + tid] = x_l[tid];   // lab part
    __syncthreads();

    for (int m = wid; m < MD_; m += 4) {
        float v = wave_dot(read_W + (size_t)m * EIN_, x_l, EIN_ / 4);
        if (lane == 0) mq_l[m] = v + read_b[m];
    }
    __syncthreads();

    float mv = mq_l[tid];
    red[tid] = mv * mv; __syncthreads();
    for (int s = 128; s > 0; s >>= 1) { if (tid < s) red[tid] += red[tid + s]; __syncthreads(); }
    float nmq = sqrtf(red[0]);

    for (int k = wid; k < KE_; k += 4) {
        float num = wave_dot(mem_k + ((size_t)b * KE_ + k) * MD_, mq_l, MD_ / 4);
        float den = fmaxf(nmq * normk[b * KE_ + k], EPS_);
        float cs = num / den;
        if (lane == 0) {
            float o = key_run[b * KE_ + k];
            key_run[b * KE_ + k] = fmaxf(o, cs);
        }
    }
}

// ---------------------------------------------------------------- key finalize + key_out
__global__ __launch_bounds__(256) void k_keyfinal(
    float* __restrict__ key_run, const void* __restrict__ kmask, float* __restrict__ d_out)
{
    int idx = blockIdx.x * 256 + threadIdx.x;    // 0..32767
    bool b8 = mask_is_b8(kmask);
    float v = key_run[idx];
    v = (v < 0.0f) ? 0.0f : v;
    key_run[idx] = v;
    d_out[O_KEY + idx] = mask_at(kmask, idx, b8) ? v : -1.0f;
}

// ---------------------------------------------------------------- val contributions (rows with rowmax >= 0.8; typically none)
__global__ __launch_bounds__(256) void k_val(
    const float* __restrict__ rowmax, const float* __restrict__ mem_k, const float* __restrict__ mem_v,
    const float* __restrict__ normk, const float* __restrict__ normv,
    const float* __restrict__ key_sim, float* __restrict__ val_sim)
{
    int idx = blockIdx.x * 256 + threadIdx.x;    // 0..32767 : (b,k)
    if (rowmax[idx] < SPARSE_) return;
    int b = idx >> 10;
    const float* krow = mem_k + (size_t)idx * MD_;
    float nk = normk[idx];
    float ks = key_sim[idx];
    float rm = -1e30f;
    for (int v = 0; v < VE_; ++v) {
        const float* vrow = mem_v + ((size_t)b * VE_ + v) * MD_;
        float d = 0.0f;
        for (int e = 0; e < MD_; ++e) d = fmaf(krow[e], vrow[e], d);
        float cs = d / fmaxf(nk * normv[b * VE_ + v], EPS_);
        rm = fmaxf(rm, cs);
    }
    float thr = fmaxf(rm, SPARSE_);
    for (int v = 0; v < VE_; ++v) {
        const float* vrow = mem_v + ((size_t)b * VE_ + v) * MD_;
        float d = 0.0f;
        for (int e = 0; e < MD_; ++e) d = fmaf(krow[e], vrow[e], d);
        float cs = d / fmaxf(nk * normv[b * VE_ + v], EPS_);
        if (cs >= thr) atomicAdd(&val_sim[(size_t)b * VE_ + v], ks * cs);
    }
}

// ---------------------------------------------------------------- val_out
__global__ __launch_bounds__(256) void k_valout(
    const float* __restrict__ val_sim, const void* __restrict__ vmask, float* __restrict__ d_out)
{
    int idx = blockIdx.x * 256 + threadIdx.x;
    bool b8 = mask_is_b8(vmask);
    d_out[O_VAL + idx] = mask_at(vmask, idx, b8) ? val_sim[idx] : -1.0f;
}

// ================================================================ launch
extern "C" void kernel_launch(void* const* d_in, const int* in_sizes, int n_in,
                              void* d_out_v, int out_size, void* d_ws, size_t ws_size,
                              hipStream_t stream)
{
    const float* enc      = (const float*)d_in[0];
    const float* hidden   = (const float*)d_in[1];
    const float* cell     = (const float*)d_in[2];
    const void*  encmask  = d_in[4];
    const void*  kmask    = d_in[5];
    const float* mem_k    = (const float*)d_in[6];
    const void*  vmask    = d_in[7];
    const float* mem_v    = (const float*)d_in[8];
    const float* W_ih     = (const float*)d_in[9];
    const float* W_hh     = (const float*)d_in[10];
    const float* b_ih     = (const float*)d_in[11];
    const float* b_hh     = (const float*)d_in[12];
    const float* mlp_W1   = (const float*)d_in[13];
    const float* mlp_b1   = (const float*)d_in[14];
    const float* mlp_W2   = (const float*)d_in[15];
    const float* mlp_b2   = (const float*)d_in[16];
    const float* emb      = (const float*)d_in[17];
    const float* dense_W  = (const float*)d_in[18];
    const float* dense_b  = (const float*)d_in[19];
    const float* read_W   = (const float*)d_in[20];
    const float* read_b   = (const float*)d_in[21];
    float* d_out = (float*)d_out_v;
    float* ws = (float*)d_ws;

    float* h       = ws;            // 32768
    float* c       = ws + 32768;    // 32768
    float* x       = ws + 65536;    // 24576
    float* g       = ws + 90112;    // 131072
    float* hid     = ws + 221184;   // 32768
    float* lmask   = ws + 253952;   // 262144
    float* sent    = ws + 516096;   // 16384
    float* pad     = ws + 532480;   // 8192
    float* key_run = ws + 540672;   // 32768
    float* val_sim = ws + 573440;   // 32768
    float* normk   = ws + 606208;   // 32768
    float* normv   = ws + 638976;   // 32768
    float* rowmax  = ws + 671744;   // 32768
    int*   nidbuf  = (int*)(ws + 704512);

    k_init<<<1024, 256, 0, stream>>>(hidden, cell, enc, encmask, h, c, x, lmask, sent, pad, key_run, val_sim);
    k_norms<<<256, 256, 0, stream>>>(mem_k, mem_v, normk, normv);
    k_rowmax<<<dim3(16, 32), 256, 0, stream>>>(mem_k, mem_v, normk, normv, rowmax);

    for (int t = 0; t < T_; ++t) {
        // gates = x@W_ih^T + h@W_hh^T + b_ih + b_hh
        k_gemm<<<G4_ / 16, 256, 0, stream>>>(x, W_ih, EIN_, h, W_hh, HD_,
                                             b_ih, b_hh, nullptr, 0, g, G4_, 0);
        k_lstm<<<128, 256, 0, stream>>>(g, h, c);
        // hid = relu(h@W1^T + b1)
        k_gemm<<<HD_ / 16, 256, 0, stream>>>(h, mlp_W1, HD_, nullptr, nullptr, 0,
                                             mlp_b1, nullptr, nullptr, 0, hid, HD_, 1);
        // logits = hid@W2^T + b2 + lmask  -> directly into d_out[:, t, :]
        k_gemm<<<N_ / 16, 256, 0, stream>>>(hid, mlp_W2, HD_, nullptr, nullptr, 0,
                                            mlp_b2, nullptr, lmask, N_,
                                            d_out + (size_t)t * N_, (long long)T_ * N_, 0);
        k_argmax<<<B_, 256, 0, stream>>>(d_out, t, nidbuf, lmask);
        k_step2<<<B_, 256, 0, stream>>>(nidbuf, emb, dense_W, dense_b, enc, pad, sent,
                                        read_W, read_b, mem_k, normk, key_run, x);
    }

    k_keyfinal<<<128, 256, 0, stream>>>(key_run, kmask, d_out);
    k_val<<<128, 256, 0, stream>>>(rowmax, mem_k, mem_v, normk, normv, key_run, val_sim);
    k_valout<<<128, 256, 0, stream>>>(val_sim, vmask, d_out);
}

// Round 3
// 7089.477 us; speedup vs baseline: 2.4672x; 2.4672x over previous
//
#include <hip/hip_runtime.h>
#include <cstdint>
#include <cstddef>

#define B_   32
#define SE_  256
#define HE_  512
#define HD_  1024
#define ED_  256
#define N_   8192
#define T_   20
#define KE_  1024
#define VE_  1024
#define MD_  256
#define EIN_ 768
#define G4_  4096
#define NEG_   (-10000000.0f)
#define MAXV_  (1000000000.0f)
#define EPS_   (1e-8f)
#define SPARSE_ 0.8f
#define GATE_  0.78f   // bf16-safe gate; pass-2 recomputes exact f32, false positives harmless

// output offsets (floats)
#define O_IDS  (B_*T_*N_)            // 5242880
#define O_KEY  (O_IDS + B_*T_)       // 5243520
#define O_VAL  (O_KEY + B_*KE_)      // 5276288

typedef __attribute__((ext_vector_type(8))) short short8;
typedef __attribute__((ext_vector_type(4))) float floatx4;

__device__ __forceinline__ float sigf(float v) { return 1.0f / (1.0f + expf(-v)); }

__device__ __forceinline__ short f2bf(float f) {
    union { float f; unsigned u; } v; v.f = f;
    unsigned r = v.u + 0x7FFFu + ((v.u >> 16) & 1u);   // RNE
    return (short)(r >> 16);
}
__device__ __forceinline__ short8 pack8(const float4 a, const float4 b) {
    short8 r;
    r[0]=f2bf(a.x); r[1]=f2bf(a.y); r[2]=f2bf(a.z); r[3]=f2bf(a.w);
    r[4]=f2bf(b.x); r[5]=f2bf(b.y); r[6]=f2bf(b.z); r[7]=f2bf(b.w);
    return r;
}

// Bool-mask layout probe (verified round 2): int32 vs packed byte.
__device__ __forceinline__ bool mask_is_b8(const void* p) {
    unsigned u = *(const unsigned*)p;
    return u > 0xFFu;
}
__device__ __forceinline__ bool mask_at(const void* p, int idx, bool b8) {
    return b8 ? (((const unsigned char*)p)[idx] != 0)
              : (((const int*)p)[idx] != 0);
}

// ---------------------------------------------------------------- init
__global__ __launch_bounds__(256) void k_init(
    const float* __restrict__ hidden, const float* __restrict__ cell,
    const float* __restrict__ enc, const void* __restrict__ encmask,
    float* __restrict__ h, float* __restrict__ c, float* __restrict__ x,
    float* __restrict__ lmask, float* __restrict__ sent, float* __restrict__ pad,
    float* __restrict__ key_run, float* __restrict__ val_sim)
{
    int idx = blockIdx.x * 256 + threadIdx.x;   // 0 .. 262143
    lmask[idx] = 0.0f;
    if (idx < B_ * HD_) {
        int b = idx >> 10, j = idx & 1023;
        int d = j >> 9, e = j & 511;
        h[idx] = hidden[((size_t)d * B_ + b) * HE_ + e];
        c[idx] = cell  [((size_t)d * B_ + b) * HE_ + e];
        key_run[idx] = -1e30f;
        val_sim[idx] = 0.0f;
    }
    if (idx < B_ * EIN_) x[idx] = 0.0f;
    if (idx < B_ * HE_) {
        int b = idx >> 9, e = idx & 511;
        sent[idx] = enc[(size_t)b * SE_ * HE_ + e];
    }
    if (idx < B_ * SE_) {
        bool b8 = mask_is_b8(encmask);
        pad[idx] = mask_at(encmask, idx, b8) ? 0.0f : -MAXV_;
    }
}

// ---------------------------------------------------------------- row norms
__global__ __launch_bounds__(256) void k_norms(
    const float* __restrict__ mem_k, const float* __restrict__ mem_v,
    float* __restrict__ normk, float* __restrict__ normv)
{
    int lane = threadIdx.x & 63;
    int wave = (blockIdx.x * 256 + threadIdx.x) >> 6;   // 0..1023
    for (int row = wave; row < 2 * B_ * KE_; row += 1024) {
        const float* base = (row < B_ * KE_) ? (mem_k + (size_t)row * MD_)
                                             : (mem_v + (size_t)(row - B_ * KE_) * MD_);
        float4 v = ((const float4*)base)[lane];
        float s = v.x*v.x + v.y*v.y + v.z*v.z + v.w*v.w;
        for (int m = 32; m; m >>= 1) s += __shfl_xor(s, m, 64);
        if (lane == 0) {
            if (row < B_ * KE_) normk[row] = sqrtf(s);
            else                normv[row - B_ * KE_] = sqrtf(s);
        }
    }
}

// ---------------------------------------------------------------- rowmax via bf16 MFMA
// grid (8 kt, 32 b), 256 thr = 4 waves. Block: 128 k-rows x all 1024 v.
// Wave: 32 k-rows (2 groups of 16). V staged per 128-row chunk in LDS (bf16, +8 pad).
__global__ __launch_bounds__(256) void k_rowmax_mfma(
    const float* __restrict__ mem_k, const float* __restrict__ mem_v,
    const float* __restrict__ normk, const float* __restrict__ normv,
    float* __restrict__ rowmax)
{
    __shared__ __align__(16) short Vs[128 * 264];
    const int tid = threadIdx.x, lane = tid & 63, w = tid >> 6;
    const int b = blockIdx.y, kt = blockIdx.x;
    const int rowbase = kt * 128 + w * 32;
    const int lrow = lane & 15, lq = lane >> 4;   // lq in 0..3

    float nk[2][4];
    #pragma unroll
    for (int rg = 0; rg < 2; ++rg)
        #pragma unroll
        for (int reg = 0; reg < 4; ++reg)
            nk[rg][reg] = normk[b * KE_ + rowbase + rg * 16 + lq * 4 + reg];

    // A fragments: A[m=lane&15][k=lq*8+j], held for whole kernel (2 rg x 8 kc)
    short8 af[2][8];
    #pragma unroll
    for (int rg = 0; rg < 2; ++rg) {
        const float* arow = mem_k + ((size_t)(b * KE_ + rowbase + rg * 16 + lrow)) * MD_;
        #pragma unroll
        for (int kc = 0; kc < 8; ++kc) {
            const float* p = arow + kc * 32 + lq * 8;
            float4 f0 = *(const float4*)p;
            float4 f1 = *(const float4*)(p + 4);
            af[rg][kc] = pack8(f0, f1);
        }
    }

    float rmax[2][4];
    #pragma unroll
    for (int rg = 0; rg < 2; ++rg)
        #pragma unroll
        for (int reg = 0; reg < 4; ++reg) rmax[rg][reg] = -1e30f;

    for (int vs = 0; vs < 8; ++vs) {
        __syncthreads();
        // stage 128 v-rows x 256 k as bf16 into LDS (row stride 264 -> 2-way max)
        #pragma unroll
        for (int i = 0; i < 16; ++i) {
            int lin = tid + i * 256;            // 0..4095 : (row, 8-col group)
            int r = lin >> 5, cg = lin & 31;
            const float* p = mem_v + ((size_t)(b * VE_ + vs * 128 + r)) * MD_ + cg * 8;
            float4 f0 = *(const float4*)p;
            float4 f1 = *(const float4*)(p + 4);
            *(short8*)&Vs[r * 264 + cg * 8] = pack8(f0, f1);
        }
        __syncthreads();

        for (int vsub = 0; vsub < 8; ++vsub) {
            float nv = normv[b * VE_ + vs * 128 + vsub * 16 + lrow];
            short8 bfr[8];
            #pragma unroll
            for (int kc = 0; kc < 8; ++kc)
                bfr[kc] = *(const short8*)&Vs[(vsub * 16 + lrow) * 264 + kc * 32 + lq * 8];
            #pragma unroll
            for (int rg = 0; rg < 2; ++rg) {
                floatx4 acc = {0.0f, 0.0f, 0.0f, 0.0f};
                #pragma unroll
                for (int kc = 0; kc < 8; ++kc)
                    acc = __builtin_amdgcn_mfma_f32_16x16x32_bf16(af[rg][kc], bfr[kc], acc, 0, 0, 0);
                // C/D: col = lane&15 (v), row = lq*4 + reg (k-row)
                #pragma unroll
                for (int reg = 0; reg < 4; ++reg) {
                    float cs = acc[reg] / fmaxf(nk[rg][reg] * nv, EPS_);
                    rmax[rg][reg] = fmaxf(rmax[rg][reg], cs);
                }
            }
        }
    }
    // reduce across the 16 columns (lanes sharing lq group)
    #pragma unroll
    for (int rg = 0; rg < 2; ++rg)
        #pragma unroll
        for (int reg = 0; reg < 4; ++reg) {
            float v = rmax[rg][reg];
            v = fmaxf(v, __shfl_xor(v, 1, 64));
            v = fmaxf(v, __shfl_xor(v, 2, 64));
            v = fmaxf(v, __shfl_xor(v, 4, 64));
            v = fmaxf(v, __shfl_xor(v, 8, 64));
            if (lrow == 0)
                rowmax[(size_t)b * KE_ + rowbase + rg * 16 + lq * 4 + reg] = v;
        }
}

// ---------------------------------------------------------------- skinny GEMM v2: X staged in LDS
// C[b,j] = X[b,:]W[j,:] over concat K=K1(+K2), + biases (+mask) (opt relu)
// 256 thr = 16 jj x 16 kg; 16 j per block; K tiled by 256 (K1,K2 multiples of 256).
__global__ __launch_bounds__(256) void k_gemm2(
    const float* __restrict__ X1, const float* __restrict__ W1, int K1,
    const float* __restrict__ X2, const float* __restrict__ W2, int K2,
    const float* __restrict__ bias1, const float* __restrict__ bias2,
    const float* __restrict__ addmask, int maskStride,
    float* __restrict__ out, long long outRowStride, int relu)
{
    __shared__ __align__(16) float Xs[32 * 256];
    __shared__ float red[16][32][17];
    const int tid = threadIdx.x;
    const int jj = tid >> 4, kg = tid & 15;
    const int j = blockIdx.x * 16 + jj;
    const int K = K1 + (X2 ? K2 : 0);

    float acc[B_];
    #pragma unroll
    for (int b = 0; b < B_; ++b) acc[b] = 0.0f;

    for (int k0 = 0; k0 < K; k0 += 256) {
        const bool second = (k0 >= K1);
        const float* Xsrc = second ? X2 : X1;
        const float* Wsrc = second ? W2 : W1;
        const int srcK = second ? K2 : K1;
        const int ks = second ? (k0 - K1) : k0;
        __syncthreads();
        #pragma unroll
        for (int i = 0; i < 8; ++i) {
            int lin = tid + i * 256;            // 0..2047 quads = 32 b x 64 q
            int b = lin >> 6, q = lin & 63;
            *(float4*)&Xs[b * 256 + q * 4] = *(const float4*)(Xsrc + (size_t)b * srcK + ks + q * 4);
        }
        __syncthreads();
        const float* Wrow = Wsrc + (size_t)j * srcK + ks;
        #pragma unroll
        for (int qq = 0; qq < 4; ++qq) {
            int qc = kg + qq * 16;              // quad col within tile
            float4 w4 = *(const float4*)(Wrow + qc * 4);
            #pragma unroll
            for (int b = 0; b < B_; ++b) {
                float4 x4 = *(const float4*)&Xs[b * 256 + qc * 4];
                acc[b] = fmaf(w4.x, x4.x, acc[b]);
                acc[b] = fmaf(w4.y, x4.y, acc[b]);
                acc[b] = fmaf(w4.z, x4.z, acc[b]);
                acc[b] = fmaf(w4.w, x4.w, acc[b]);
            }
        }
    }
    #pragma unroll
    for (int b = 0; b < B_; ++b) red[jj][b][kg] = acc[b];
    __syncthreads();
    for (int o = tid; o < 16 * B_; o += 256) {
        int jjo = o >> 5, b = o & 31;
        float s = 0.0f;
        #pragma unroll
        for (int k = 0; k < 16; ++k) s += red[jjo][b][k];
        int jo = blockIdx.x * 16 + jjo;
        s += bias1[jo];
        if (bias2) s += bias2[jo];
        if (addmask) s += addmask[(size_t)b * maskStride + jo];
        if (relu) s = fmaxf(s, 0.0f);
        out[(size_t)b * outRowStride + jo] = s;
    }
}

// ---------------------------------------------------------------- LSTM pointwise
__global__ __launch_bounds__(256) void k_lstm(
    const float* __restrict__ g, float* __restrict__ h, float* __restrict__ c)
{
    int idx = blockIdx.x * 256 + threadIdx.x;       // 0..32767
    int b = idx >> 10, j = idx & 1023;
    const float* gb = g + (size_t)b * G4_;
    float gi = gb[j], gf = gb[HD_ + j], gg = gb[2 * HD_ + j], go = gb[3 * HD_ + j];
    float c1 = sigf(gf) * c[idx] + sigf(gi) * tanhf(gg);
    h[idx] = sigf(go) * tanhf(c1);
    c[idx] = c1;
}

// ---------------------------------------------------------------- argmax + lmask update
__global__ __launch_bounds__(256) void k_argmax(
    float* __restrict__ d_out, int t, int* __restrict__ nidbuf, float* __restrict__ lmask)
{
    __shared__ float sv[256];
    __shared__ int   si[256];
    const int b = blockIdx.x, tid = threadIdx.x;
    const float* lg = d_out + ((size_t)b * T_ + t) * N_;
    float best = -1e38f; int bi = 0;
    for (int j = tid; j < N_; j += 256) {
        float v = lg[j];
        if (v > best) { best = v; bi = j; }
    }
    sv[tid] = best; si[tid] = bi;
    __syncthreads();
    for (int s = 128; s > 0; s >>= 1) {
        if (tid < s) {
            float v2 = sv[tid + s]; int i2 = si[tid + s];
            if (v2 > sv[tid] || (v2 == sv[tid] && i2 < si[tid])) { sv[tid] = v2; si[tid] = i2; }
        }
        __syncthreads();
    }
    if (tid == 0) {
        int nid = si[0];
        nidbuf[b] = nid;
        d_out[O_IDS + (size_t)b * T_ + t] = (float)nid;
        lmask[(size_t)b * N_ + nid] = NEG_;
        lmask[(size_t)b * N_] = 0.0f;
    }
}

// ---------------------------------------------------------------- wave dot helper
__device__ __forceinline__ float wave_dot(const float* __restrict__ row, const float* vl, int quads)
{
    int lane = threadIdx.x & 63;
    float s = 0.0f;
    for (int q = lane; q < quads; q += 64) {
        float4 a = ((const float4*)row)[q];
        float4 x = ((const float4*)vl)[q];
        s = fmaf(a.x, x.x, s); s = fmaf(a.y, x.y, s);
        s = fmaf(a.z, x.z, s); s = fmaf(a.w, x.w, s);
    }
    for (int m = 32; m; m >>= 1) s += __shfl_xor(s, m, 64);
    return s;
}

// ---------------------------------------------------------------- step tail: emb, attention, x, mq (sequential chain, per-b block)
__global__ __launch_bounds__(256) void k_step2a(
    const int* __restrict__ nidbuf, const float* __restrict__ emb,
    const float* __restrict__ dense_W, const float* __restrict__ dense_b,
    const float* __restrict__ enc, const float* __restrict__ pad,
    const float* __restrict__ sent,
    const float* __restrict__ read_W, const float* __restrict__ read_b,
    float* __restrict__ xg, float* __restrict__ mqg, float* __restrict__ nmqg)
{
    __shared__ __align__(16) float x_l[EIN_];
    __shared__ __align__(16) float q_l[HE_];
    __shared__ __align__(16) float sc_l[SE_];
    __shared__ __align__(16) float w_l[SE_];
    __shared__ __align__(16) float mq_l[MD_];
    __shared__ float red[256];
    const int b = blockIdx.x, tid = threadIdx.x;
    const int wid = tid >> 6, lane = tid & 63;

    int nid = nidbuf[b];
    x_l[tid] = emb[(size_t)nid * ED_ + tid];
    __syncthreads();

    for (int j = wid; j < HE_; j += 4) {
        float v = wave_dot(dense_W + (size_t)j * ED_, x_l, ED_ / 4);
        if (lane == 0) q_l[j] = v + dense_b[j];
    }
    __syncthreads();

    for (int s = wid; s < SE_; s += 4) {
        float v = wave_dot(enc + ((size_t)b * SE_ + s) * HE_, q_l, HE_ / 4);
        if (lane == 0) sc_l[s] = v + pad[b * SE_ + s];
    }
    __syncthreads();

    float sv = sc_l[tid];
    red[tid] = sv; __syncthreads();
    for (int s = 128; s > 0; s >>= 1) { if (tid < s) red[tid] = fmaxf(red[tid], red[tid + s]); __syncthreads(); }
    float mx = red[0]; __syncthreads();
    float ev = expf(sv - mx);
    red[tid] = ev; __syncthreads();
    for (int s = 128; s > 0; s >>= 1) { if (tid < s) red[tid] += red[tid + s]; __syncthreads(); }
    float inv = 1.0f / red[0];
    w_l[tid] = ev * inv;
    __syncthreads();

    for (int ee = tid; ee < HE_; ee += 256) {
        float a = 0.0f;
        for (int s = 0; s < SE_; ++s) a = fmaf(w_l[s], enc[((size_t)b * SE_ + s) * HE_ + ee], a);
        float xv = sent[b * HE_ + ee] + a;
        x_l[ED_ + ee] = xv;
        xg[(size_t)b * EIN_ + ED_ + ee] = xv;
    }
    xg[(size_t)b * EIN_ + tid] = x_l[tid];   // lab part
    __syncthreads();

    for (int m = wid; m < MD_; m += 4) {
        float v = wave_dot(read_W + (size_t)m * EIN_, x_l, EIN_ / 4);
        if (lane == 0) mq_l[m] = v + read_b[m];
    }
    __syncthreads();

    float mv = mq_l[tid];
    red[tid] = mv * mv; __syncthreads();
    for (int s = 128; s > 0; s >>= 1) { if (tid < s) red[tid] += red[tid + s]; __syncthreads(); }
    float nmq = sqrtf(red[0]);

    mqg[(size_t)b * MD_ + tid] = mq_l[tid];
    if (tid == 0) nmqg[b] = nmq;
}

// ---------------------------------------------------------------- ksim: cos(mq, mem_k) running max — parallel over (b, k-tiles)
__global__ __launch_bounds__(256) void k_ksim(
    const float* __restrict__ mqg, const float* __restrict__ nmqg,
    const float* __restrict__ mem_k, const float* __restrict__ normk,
    float* __restrict__ key_run)
{
    __shared__ __align__(16) float mql[MD_];
    const int b = blockIdx.y, kt = blockIdx.x;    // kt 0..7
    const int tid = threadIdx.x, lane = tid & 63, w = tid >> 6;
    mql[tid] = mqg[(size_t)b * MD_ + tid];
    __syncthreads();
    float nmq = nmqg[b];
    int base = kt * 128 + w * 32;
    for (int i = 0; i < 32; ++i) {
        int k = base + i;
        float num = wave_dot(mem_k + ((size_t)b * KE_ + k) * MD_, mql, MD_ / 4);
        if (lane == 0) {
            float cs = num / fmaxf(nmq * normk[b * KE_ + k], EPS_);
            float o = key_run[b * KE_ + k];
            key_run[b * KE_ + k] = fmaxf(o, cs);
        }
    }
}

// ---------------------------------------------------------------- key finalize + key_out
__global__ __launch_bounds__(256) void k_keyfinal(
    float* __restrict__ key_run, const void* __restrict__ kmask, float* __restrict__ d_out)
{
    int idx = blockIdx.x * 256 + threadIdx.x;    // 0..32767
    bool b8 = mask_is_b8(kmask);
    float v = key_run[idx];
    v = (v < 0.0f) ? 0.0f : v;
    key_run[idx] = v;
    d_out[O_KEY + idx] = mask_at(kmask, idx, b8) ? v : -1.0f;
}

// ---------------------------------------------------------------- val contributions (rows gated by bf16 rowmax; exact f32 recompute)
__global__ __launch_bounds__(256) void k_val(
    const float* __restrict__ rowmax, const float* __restrict__ mem_k, const float* __restrict__ mem_v,
    const float* __restrict__ normk, const float* __restrict__ normv,
    const float* __restrict__ key_sim, float* __restrict__ val_sim)
{
    int idx = blockIdx.x * 256 + threadIdx.x;    // 0..32767 : (b,k)
    if (rowmax[idx] < GATE_) return;
    int b = idx >> 10;
    const float* krow = mem_k + (size_t)idx * MD_;
    float nk = normk[idx];
    float ks = key_sim[idx];
    float rm = -1e30f;
    for (int v = 0; v < VE_; ++v) {
        const float* vrow = mem_v + ((size_t)b * VE_ + v) * MD_;
        float d = 0.0f;
        for (int e = 0; e < MD_; ++e) d = fmaf(krow[e], vrow[e], d);
        float cs = d / fmaxf(nk * normv[b * VE_ + v], EPS_);
        rm = fmaxf(rm, cs);
    }
    float thr = fmaxf(rm, SPARSE_);
    for (int v = 0; v < VE_; ++v) {
        const float* vrow = mem_v + ((size_t)b * VE_ + v) * MD_;
        float d = 0.0f;
        for (int e = 0; e < MD_; ++e) d = fmaf(krow[e], vrow[e], d);
        float cs = d / fmaxf(nk * normv[b * VE_ + v], EPS_);
        if (cs >= thr) atomicAdd(&val_sim[(size_t)b * VE_ + v], ks * cs);
    }
}

// ---------------------------------------------------------------- val_out
__global__ __launch_bounds__(256) void k_valout(
    const float* __restrict__ val_sim, const void* __restrict__ vmask, float* __restrict__ d_out)
{
    int idx = blockIdx.x * 256 + threadIdx.x;
    bool b8 = mask_is_b8(vmask);
    d_out[O_VAL + idx] = mask_at(vmask, idx, b8) ? val_sim[idx] : -1.0f;
}

// ================================================================ launch
extern "C" void kernel_launch(void* const* d_in, const int* in_sizes, int n_in,
                              void* d_out_v, int out_size, void* d_ws, size_t ws_size,
                              hipStream_t stream)
{
    const float* enc      = (const float*)d_in[0];
    const float* hidden   = (const float*)d_in[1];
    const float* cell     = (const float*)d_in[2];
    const void*  encmask  = d_in[4];
    const void*  kmask    = d_in[5];
    const float* mem_k    = (const float*)d_in[6];
    const void*  vmask    = d_in[7];
    const float* mem_v    = (const float*)d_in[8];
    const float* W_ih     = (const float*)d_in[9];
    const float* W_hh     = (const float*)d_in[10];
    const float* b_ih     = (const float*)d_in[11];
    const float* b_hh     = (const float*)d_in[12];
    const float* mlp_W1   = (const float*)d_in[13];
    const float* mlp_b1   = (const float*)d_in[14];
    const float* mlp_W2   = (const float*)d_in[15];
    const float* mlp_b2   = (const float*)d_in[16];
    const float* emb      = (const float*)d_in[17];
    const float* dense_W  = (const float*)d_in[18];
    const float* dense_b  = (const float*)d_in[19];
    const float* read_W   = (const float*)d_in[20];
    const float* read_b   = (const float*)d_in[21];
    float* d_out = (float*)d_out_v;
    float* ws = (float*)d_ws;

    float* h       = ws;            // 32768
    float* c       = ws + 32768;    // 32768
    float* x       = ws + 65536;    // 24576
    float* g       = ws + 90112;    // 131072
    float* hid     = ws + 221184;   // 32768
    float* lmask   = ws + 253952;   // 262144
    float* sent    = ws + 516096;   // 16384
    float* pad     = ws + 532480;   // 8192
    float* key_run = ws + 540672;   // 32768
    float* val_sim = ws + 573440;   // 32768
    float* normk   = ws + 606208;   // 32768
    float* normv   = ws + 638976;   // 32768
    float* rowmax  = ws + 671744;   // 32768
    int*   nidbuf  = (int*)(ws + 704512);  // 32 ints
    float* mqg     = ws + 704576;   // 8192
    float* nmqg    = ws + 712768;   // 32

    k_init<<<1024, 256, 0, stream>>>(hidden, cell, enc, encmask, h, c, x, lmask, sent, pad, key_run, val_sim);
    k_norms<<<256, 256, 0, stream>>>(mem_k, mem_v, normk, normv);
    k_rowmax_mfma<<<dim3(8, 32), 256, 0, stream>>>(mem_k, mem_v, normk, normv, rowmax);

    for (int t = 0; t < T_; ++t) {
        // gates = x@W_ih^T + h@W_hh^T + b_ih + b_hh   (K = 768 + 1024)
        k_gemm2<<<G4_ / 16, 256, 0, stream>>>(x, W_ih, EIN_, h, W_hh, HD_,
                                              b_ih, b_hh, nullptr, 0, g, G4_, 0);
        k_lstm<<<128, 256, 0, stream>>>(g, h, c);
        // hid = relu(h@W1^T + b1)
        k_gemm2<<<HD_ / 16, 256, 0, stream>>>(h, mlp_W1, HD_, nullptr, nullptr, 0,
                                              mlp_b1, nullptr, nullptr, 0, hid, HD_, 1);
        // logits = hid@W2^T + b2 + lmask  -> d_out[:, t, :]
        k_gemm2<<<N_ / 16, 256, 0, stream>>>(hid, mlp_W2, HD_, nullptr, nullptr, 0,
                                             mlp_b2, nullptr, lmask, N_,
                                             d_out + (size_t)t * N_, (long long)T_ * N_, 0);
        k_argmax<<<B_, 256, 0, stream>>>(d_out, t, nidbuf, lmask);
        k_step2a<<<B_, 256, 0, stream>>>(nidbuf, emb, dense_W, dense_b, enc, pad, sent,
                                         read_W, read_b, x, mqg, nmqg);
        k_ksim<<<dim3(8, B_), 256, 0, stream>>>(mqg, nmqg, mem_k, normk, key_run);
    }

    k_keyfinal<<<128, 256, 0, stream>>>(key_run, kmask, d_out);
    k_val<<<128, 256, 0, stream>>>(rowmax, mem_k, mem_v, normk, normv, key_run, val_sim);
    k_valout<<<128, 256, 0, stream>>>(val_sim, vmask, d_out);
}

// Round 4
// 3739.752 us; speedup vs baseline: 4.6770x; 1.8957x over previous
//
#include <hip/hip_runtime.h>
#include <cstdint>
#include <cstddef>

#define B_   32
#define SE_  256
#define HE_  512
#define HD_  1024
#define ED_  256
#define N_   8192
#define T_   20
#define KE_  1024
#define VE_  1024
#define MD_  256
#define EIN_ 768
#define G4_  4096
#define NEG_   (-10000000.0f)
#define MAXV_  (1000000000.0f)
#define EPS_   (1e-8f)
#define SPARSE_ 0.8f
#define GATE_  0.78f   // bf16-safe gate; pass-2 recomputes exact f32, false positives harmless

// output offsets (floats)
#define O_IDS  (B_*T_*N_)            // 5242880
#define O_KEY  (O_IDS + B_*T_)       // 5243520
#define O_VAL  (O_KEY + B_*KE_)      // 5276288

typedef __attribute__((ext_vector_type(8))) short short8;
typedef __attribute__((ext_vector_type(4))) float floatx4;

__device__ __forceinline__ float sigf(float v) { return 1.0f / (1.0f + expf(-v)); }

__device__ __forceinline__ short f2bf(float f) {
    union { float f; unsigned u; } v; v.f = f;
    unsigned r = v.u + 0x7FFFu + ((v.u >> 16) & 1u);   // RNE
    return (short)(r >> 16);
}
__device__ __forceinline__ short8 pack8(const float4 a, const float4 b) {
    short8 r;
    r[0]=f2bf(a.x); r[1]=f2bf(a.y); r[2]=f2bf(a.z); r[3]=f2bf(a.w);
    r[4]=f2bf(b.x); r[5]=f2bf(b.y); r[6]=f2bf(b.z); r[7]=f2bf(b.w);
    return r;
}

// Bool-mask layout probe (verified round 2): int32 vs packed byte.
__device__ __forceinline__ bool mask_is_b8(const void* p) {
    unsigned u = *(const unsigned*)p;
    return u > 0xFFu;
}
__device__ __forceinline__ bool mask_at(const void* p, int idx, bool b8) {
    return b8 ? (((const unsigned char*)p)[idx] != 0)
              : (((const int*)p)[idx] != 0);
}

// ---------------------------------------------------------------- init
__global__ __launch_bounds__(256) void k_init(
    const float* __restrict__ hidden, const float* __restrict__ cell,
    const float* __restrict__ enc, const void* __restrict__ encmask,
    float* __restrict__ h, float* __restrict__ c, float* __restrict__ x,
    float* __restrict__ lmask, float* __restrict__ sent, float* __restrict__ pad,
    float* __restrict__ key_run, float* __restrict__ val_sim)
{
    int idx = blockIdx.x * 256 + threadIdx.x;   // 0 .. 262143
    lmask[idx] = 0.0f;
    if (idx < B_ * HD_) {
        int b = idx >> 10, j = idx & 1023;
        int d = j >> 9, e = j & 511;
        h[idx] = hidden[((size_t)d * B_ + b) * HE_ + e];
        c[idx] = cell  [((size_t)d * B_ + b) * HE_ + e];
        key_run[idx] = -1e30f;
        val_sim[idx] = 0.0f;
    }
    if (idx < B_ * EIN_) x[idx] = 0.0f;
    if (idx < B_ * HE_) {
        int b = idx >> 9, e = idx & 511;
        sent[idx] = enc[(size_t)b * SE_ * HE_ + e];
    }
    if (idx < B_ * SE_) {
        bool b8 = mask_is_b8(encmask);
        pad[idx] = mask_at(encmask, idx, b8) ? 0.0f : -MAXV_;
    }
}

// ---------------------------------------------------------------- row norms
__global__ __launch_bounds__(256) void k_norms(
    const float* __restrict__ mem_k, const float* __restrict__ mem_v,
    float* __restrict__ normk, float* __restrict__ normv)
{
    int lane = threadIdx.x & 63;
    int wave = (blockIdx.x * 256 + threadIdx.x) >> 6;   // 0..1023
    for (int row = wave; row < 2 * B_ * KE_; row += 1024) {
        const float* base = (row < B_ * KE_) ? (mem_k + (size_t)row * MD_)
                                             : (mem_v + (size_t)(row - B_ * KE_) * MD_);
        float4 v = ((const float4*)base)[lane];
        float s = v.x*v.x + v.y*v.y + v.z*v.z + v.w*v.w;
        for (int m = 32; m; m >>= 1) s += __shfl_xor(s, m, 64);
        if (lane == 0) {
            if (row < B_ * KE_) normk[row] = sqrtf(s);
            else                normv[row - B_ * KE_] = sqrtf(s);
        }
    }
}

// ---------------------------------------------------------------- rowmax via bf16 MFMA
__global__ __launch_bounds__(256) void k_rowmax_mfma(
    const float* __restrict__ mem_k, const float* __restrict__ mem_v,
    const float* __restrict__ normk, const float* __restrict__ normv,
    float* __restrict__ rowmax)
{
    __shared__ __align__(16) short Vs[128 * 264];
    const int tid = threadIdx.x, lane = tid & 63, w = tid >> 6;
    const int b = blockIdx.y, kt = blockIdx.x;
    const int rowbase = kt * 128 + w * 32;
    const int lrow = lane & 15, lq = lane >> 4;   // lq in 0..3

    float nk[2][4];
    #pragma unroll
    for (int rg = 0; rg < 2; ++rg)
        #pragma unroll
        for (int reg = 0; reg < 4; ++reg)
            nk[rg][reg] = normk[b * KE_ + rowbase + rg * 16 + lq * 4 + reg];

    short8 af[2][8];
    #pragma unroll
    for (int rg = 0; rg < 2; ++rg) {
        const float* arow = mem_k + ((size_t)(b * KE_ + rowbase + rg * 16 + lrow)) * MD_;
        #pragma unroll
        for (int kc = 0; kc < 8; ++kc) {
            const float* p = arow + kc * 32 + lq * 8;
            float4 f0 = *(const float4*)p;
            float4 f1 = *(const float4*)(p + 4);
            af[rg][kc] = pack8(f0, f1);
        }
    }

    float rmax[2][4];
    #pragma unroll
    for (int rg = 0; rg < 2; ++rg)
        #pragma unroll
        for (int reg = 0; reg < 4; ++reg) rmax[rg][reg] = -1e30f;

    for (int vs = 0; vs < 8; ++vs) {
        __syncthreads();
        #pragma unroll
        for (int i = 0; i < 16; ++i) {
            int lin = tid + i * 256;
            int r = lin >> 5, cg = lin & 31;
            const float* p = mem_v + ((size_t)(b * VE_ + vs * 128 + r)) * MD_ + cg * 8;
            float4 f0 = *(const float4*)p;
            float4 f1 = *(const float4*)(p + 4);
            *(short8*)&Vs[r * 264 + cg * 8] = pack8(f0, f1);
        }
        __syncthreads();

        for (int vsub = 0; vsub < 8; ++vsub) {
            float nv = normv[b * VE_ + vs * 128 + vsub * 16 + lrow];
            short8 bfr[8];
            #pragma unroll
            for (int kc = 0; kc < 8; ++kc)
                bfr[kc] = *(const short8*)&Vs[(vsub * 16 + lrow) * 264 + kc * 32 + lq * 8];
            #pragma unroll
            for (int rg = 0; rg < 2; ++rg) {
                floatx4 acc = {0.0f, 0.0f, 0.0f, 0.0f};
                #pragma unroll
                for (int kc = 0; kc < 8; ++kc)
                    acc = __builtin_amdgcn_mfma_f32_16x16x32_bf16(af[rg][kc], bfr[kc], acc, 0, 0, 0);
                #pragma unroll
                for (int reg = 0; reg < 4; ++reg) {
                    float cs = acc[reg] / fmaxf(nk[rg][reg] * nv, EPS_);
                    rmax[rg][reg] = fmaxf(rmax[rg][reg], cs);
                }
            }
        }
    }
    #pragma unroll
    for (int rg = 0; rg < 2; ++rg)
        #pragma unroll
        for (int reg = 0; reg < 4; ++reg) {
            float v = rmax[rg][reg];
            v = fmaxf(v, __shfl_xor(v, 1, 64));
            v = fmaxf(v, __shfl_xor(v, 2, 64));
            v = fmaxf(v, __shfl_xor(v, 4, 64));
            v = fmaxf(v, __shfl_xor(v, 8, 64));
            if (lrow == 0)
                rowmax[(size_t)b * KE_ + rowbase + rg * 16 + lq * 4 + reg] = v;
        }
}

// ---------------------------------------------------------------- skinny GEMM v2: X staged in LDS, optional row-gather
__global__ __launch_bounds__(256) void k_gemm2(
    const float* __restrict__ X1, const float* __restrict__ W1, int K1,
    const float* __restrict__ X2, const float* __restrict__ W2, int K2,
    const float* __restrict__ bias1, const float* __restrict__ bias2,
    const float* __restrict__ addmask, int maskStride,
    float* __restrict__ out, long long outRowStride, int relu,
    const int* __restrict__ xidx)
{
    __shared__ __align__(16) float Xs[32 * 256];
    __shared__ float red[16][32][17];
    const int tid = threadIdx.x;
    const int jj = tid >> 4, kg = tid & 15;
    const int j = blockIdx.x * 16 + jj;
    const int K = K1 + (X2 ? K2 : 0);

    float acc[B_];
    #pragma unroll
    for (int b = 0; b < B_; ++b) acc[b] = 0.0f;

    for (int k0 = 0; k0 < K; k0 += 256) {
        const bool second = (k0 >= K1);
        const float* Xsrc = second ? X2 : X1;
        const float* Wsrc = second ? W2 : W1;
        const int srcK = second ? K2 : K1;
        const int ks = second ? (k0 - K1) : k0;
        __syncthreads();
        #pragma unroll
        for (int i = 0; i < 8; ++i) {
            int lin = tid + i * 256;            // 0..2047 quads = 32 b x 64 q
            int b = lin >> 6, q = lin & 63;
            size_t rowbase = ((!second && xidx) ? (size_t)xidx[b] : (size_t)b) * srcK;
            *(float4*)&Xs[b * 256 + q * 4] = *(const float4*)(Xsrc + rowbase + ks + q * 4);
        }
        __syncthreads();
        const float* Wrow = Wsrc + (size_t)j * srcK + ks;
        #pragma unroll
        for (int qq = 0; qq < 4; ++qq) {
            int qc = kg + qq * 16;
            float4 w4 = *(const float4*)(Wrow + qc * 4);
            #pragma unroll
            for (int b = 0; b < B_; ++b) {
                float4 x4 = *(const float4*)&Xs[b * 256 + qc * 4];
                acc[b] = fmaf(w4.x, x4.x, acc[b]);
                acc[b] = fmaf(w4.y, x4.y, acc[b]);
                acc[b] = fmaf(w4.z, x4.z, acc[b]);
                acc[b] = fmaf(w4.w, x4.w, acc[b]);
            }
        }
    }
    #pragma unroll
    for (int b = 0; b < B_; ++b) red[jj][b][kg] = acc[b];
    __syncthreads();
    for (int o = tid; o < 16 * B_; o += 256) {
        int jjo = o >> 5, b = o & 31;
        float s = 0.0f;
        #pragma unroll
        for (int k = 0; k < 16; ++k) s += red[jjo][b][k];
        int jo = blockIdx.x * 16 + jjo;
        s += bias1[jo];
        if (bias2) s += bias2[jo];
        if (addmask) s += addmask[(size_t)b * maskStride + jo];
        if (relu) s = fmaxf(s, 0.0f);
        out[(size_t)b * outRowStride + jo] = s;
    }
}

// ---------------------------------------------------------------- LSTM pointwise
__global__ __launch_bounds__(256) void k_lstm(
    const float* __restrict__ g, float* __restrict__ h, float* __restrict__ c)
{
    int idx = blockIdx.x * 256 + threadIdx.x;       // 0..32767
    int b = idx >> 10, j = idx & 1023;
    const float* gb = g + (size_t)b * G4_;
    float gi = gb[j], gf = gb[HD_ + j], gg = gb[2 * HD_ + j], go = gb[3 * HD_ + j];
    float c1 = sigf(gf) * c[idx] + sigf(gi) * tanhf(gg);
    h[idx] = sigf(go) * tanhf(c1);
    c[idx] = c1;
}

// ---------------------------------------------------------------- argmax + lmask update
__global__ __launch_bounds__(256) void k_argmax(
    float* __restrict__ d_out, int t, int* __restrict__ nidbuf, float* __restrict__ lmask)
{
    __shared__ float sv[256];
    __shared__ int   si[256];
    const int b = blockIdx.x, tid = threadIdx.x;
    const float* lg = d_out + ((size_t)b * T_ + t) * N_;
    float best = -1e38f; int bi = 0;
    for (int j = tid; j < N_; j += 256) {
        float v = lg[j];
        if (v > best) { best = v; bi = j; }
    }
    sv[tid] = best; si[tid] = bi;
    __syncthreads();
    for (int s = 128; s > 0; s >>= 1) {
        if (tid < s) {
            float v2 = sv[tid + s]; int i2 = si[tid + s];
            if (v2 > sv[tid] || (v2 == sv[tid] && i2 < si[tid])) { sv[tid] = v2; si[tid] = i2; }
        }
        __syncthreads();
    }
    if (tid == 0) {
        int nid = si[0];
        nidbuf[b] = nid;
        d_out[O_IDS + (size_t)b * T_ + t] = (float)nid;
        lmask[(size_t)b * N_ + nid] = NEG_;
        lmask[(size_t)b * N_] = 0.0f;
    }
}

// ---------------------------------------------------------------- wave dot helper (global row x LDS vec)
__device__ __forceinline__ float wave_dot(const float* __restrict__ row, const float* vl, int quads)
{
    int lane = threadIdx.x & 63;
    float s = 0.0f;
    for (int q = lane; q < quads; q += 64) {
        float4 a = ((const float4*)row)[q];
        float4 x = ((const float4*)vl)[q];
        s = fmaf(a.x, x.x, s); s = fmaf(a.y, x.y, s);
        s = fmaf(a.z, x.z, s); s = fmaf(a.w, x.w, s);
    }
    for (int m = 32; m; m >>= 1) s += __shfl_xor(s, m, 64);
    return s;
}

// ---------------------------------------------------------------- attn pass 1: per 32-s chunk scores + online-softmax partials
// grid (sc=8, b=32), 256 thr. part row (per b,sc): 512 attn partials + m + esum (stride 516)
__global__ __launch_bounds__(256) void k_attn1(
    const float* __restrict__ qg, const float* __restrict__ enc,
    const float* __restrict__ pad, float* __restrict__ part)
{
    __shared__ __align__(16) float ql[HE_];
    __shared__ float sc_l[32];
    __shared__ float wp_l[32];
    const int b = blockIdx.y, sc = blockIdx.x;
    const int tid = threadIdx.x, lane = tid & 63, w = tid >> 6;
    ql[tid] = qg[(size_t)b * HE_ + tid];
    ql[tid + 256] = qg[(size_t)b * HE_ + tid + 256];
    __syncthreads();

    // scores: wave w handles s_local = w + 4*i
    #pragma unroll
    for (int i = 0; i < 8; ++i) {
        int sl = w + i * 4;
        int s = sc * 32 + sl;
        float v = wave_dot(enc + ((size_t)b * SE_ + s) * HE_, ql, HE_ / 4);
        if (lane == 0) sc_l[sl] = v + pad[b * SE_ + s];
    }
    __syncthreads();

    float m = -1e38f;
    #pragma unroll
    for (int i = 0; i < 32; ++i) m = fmaxf(m, sc_l[i]);
    if (tid < 32) wp_l[tid] = expf(sc_l[tid] - m);
    __syncthreads();
    float esum = 0.0f;
    #pragma unroll
    for (int i = 0; i < 32; ++i) esum += wp_l[i];

    float a0 = 0.0f, a1 = 0.0f;
    for (int i = 0; i < 32; ++i) {
        float wv = wp_l[i];
        const float* er = enc + ((size_t)b * SE_ + sc * 32 + i) * HE_;
        a0 = fmaf(wv, er[tid], a0);
        a1 = fmaf(wv, er[tid + 256], a1);
    }
    float* pb = part + ((size_t)b * 8 + sc) * 516;
    pb[tid] = a0;
    pb[256 + tid] = a1;
    if (tid == 0) { pb[512] = m; pb[513] = esum; }
}

// ---------------------------------------------------------------- attn pass 2: merge 8 chunks, build x = [lab | sent+attn]
__global__ __launch_bounds__(256) void k_attn2(
    const float* __restrict__ part, const float* __restrict__ sent,
    const int* __restrict__ nidbuf, const float* __restrict__ emb,
    float* __restrict__ xg)
{
    __shared__ float ms[8], es[8];
    const int b = blockIdx.x, tid = threadIdx.x;
    if (tid < 8) {
        ms[tid] = part[((size_t)b * 8 + tid) * 516 + 512];
        es[tid] = part[((size_t)b * 8 + tid) * 516 + 513];
    }
    __syncthreads();
    float m = -1e38f;
    #pragma unroll
    for (int c = 0; c < 8; ++c) m = fmaxf(m, ms[c]);
    float scale[8];
    float denom = 0.0f;
    #pragma unroll
    for (int c = 0; c < 8; ++c) { scale[c] = expf(ms[c] - m); denom += es[c] * scale[c]; }
    float inv = 1.0f / denom;
    float a0 = 0.0f, a1 = 0.0f;
    #pragma unroll
    for (int c = 0; c < 8; ++c) {
        const float* pb = part + ((size_t)b * 8 + c) * 516;
        a0 = fmaf(scale[c], pb[tid], a0);
        a1 = fmaf(scale[c], pb[256 + tid], a1);
    }
    a0 *= inv; a1 *= inv;
    float* xr = xg + (size_t)b * EIN_;
    xr[tid] = emb[(size_t)nidbuf[b] * ED_ + tid];                 // lab
    xr[ED_ + tid]       = sent[(size_t)b * HE_ + tid]       + a0; // sent+attn
    xr[ED_ + 256 + tid] = sent[(size_t)b * HE_ + 256 + tid] + a1;
}

// ---------------------------------------------------------------- ksim: cos(mq, mem_k) running max — grid (16 kt, 32 b)
__global__ __launch_bounds__(256) void k_ksim(
    const float* __restrict__ mqg,
    const float* __restrict__ mem_k, const float* __restrict__ normk,
    float* __restrict__ key_run)
{
    __shared__ __align__(16) float mql[MD_];
    __shared__ float red[256];
    const int b = blockIdx.y, kt = blockIdx.x;    // kt 0..15
    const int tid = threadIdx.x, lane = tid & 63, w = tid >> 6;
    float mv = mqg[(size_t)b * MD_ + tid];
    mql[tid] = mv;
    red[tid] = mv * mv;
    __syncthreads();
    for (int s = 128; s > 0; s >>= 1) { if (tid < s) red[tid] += red[tid + s]; __syncthreads(); }
    float nmq = sqrtf(red[0]);

    int base = kt * 64 + w * 16;
    for (int i = 0; i < 16; ++i) {
        int k = base + i;
        float num = wave_dot(mem_k + ((size_t)b * KE_ + k) * MD_, mql, MD_ / 4);
        if (lane == 0) {
            float cs = num / fmaxf(nmq * normk[b * KE_ + k], EPS_);
            float o = key_run[b * KE_ + k];
            key_run[b * KE_ + k] = fmaxf(o, cs);
        }
    }
}

// ---------------------------------------------------------------- key finalize + key_out
__global__ __launch_bounds__(256) void k_keyfinal(
    float* __restrict__ key_run, const void* __restrict__ kmask, float* __restrict__ d_out)
{
    int idx = blockIdx.x * 256 + threadIdx.x;    // 0..32767
    bool b8 = mask_is_b8(kmask);
    float v = key_run[idx];
    v = (v < 0.0f) ? 0.0f : v;
    key_run[idx] = v;
    d_out[O_KEY + idx] = mask_at(kmask, idx, b8) ? v : -1.0f;
}

// ---------------------------------------------------------------- val contributions (rows gated by bf16 rowmax; exact f32 recompute)
__global__ __launch_bounds__(256) void k_val(
    const float* __restrict__ rowmax, const float* __restrict__ mem_k, const float* __restrict__ mem_v,
    const float* __restrict__ normk, const float* __restrict__ normv,
    const float* __restrict__ key_sim, float* __restrict__ val_sim)
{
    int idx = blockIdx.x * 256 + threadIdx.x;    // 0..32767 : (b,k)
    if (rowmax[idx] < GATE_) return;
    int b = idx >> 10;
    const float* krow = mem_k + (size_t)idx * MD_;
    float nk = normk[idx];
    float ks = key_sim[idx];
    float rm = -1e30f;
    for (int v = 0; v < VE_; ++v) {
        const float* vrow = mem_v + ((size_t)b * VE_ + v) * MD_;
        float d = 0.0f;
        for (int e = 0; e < MD_; ++e) d = fmaf(krow[e], vrow[e], d);
        float cs = d / fmaxf(nk * normv[b * VE_ + v], EPS_);
        rm = fmaxf(rm, cs);
    }
    float thr = fmaxf(rm, SPARSE_);
    for (int v = 0; v < VE_; ++v) {
        const float* vrow = mem_v + ((size_t)b * VE_ + v) * MD_;
        float d = 0.0f;
        for (int e = 0; e < MD_; ++e) d = fmaf(krow[e], vrow[e], d);
        float cs = d / fmaxf(nk * normv[b * VE_ + v], EPS_);
        if (cs >= thr) atomicAdd(&val_sim[(size_t)b * VE_ + v], ks * cs);
    }
}

// ---------------------------------------------------------------- val_out
__global__ __launch_bounds__(256) void k_valout(
    const float* __restrict__ val_sim, const void* __restrict__ vmask, float* __restrict__ d_out)
{
    int idx = blockIdx.x * 256 + threadIdx.x;
    bool b8 = mask_is_b8(vmask);
    d_out[O_VAL + idx] = mask_at(vmask, idx, b8) ? val_sim[idx] : -1.0f;
}

// ================================================================ launch
extern "C" void kernel_launch(void* const* d_in, const int* in_sizes, int n_in,
                              void* d_out_v, int out_size, void* d_ws, size_t ws_size,
                              hipStream_t stream)
{
    const float* enc      = (const float*)d_in[0];
    const float* hidden   = (const float*)d_in[1];
    const float* cell     = (const float*)d_in[2];
    const void*  encmask  = d_in[4];
    const void*  kmask    = d_in[5];
    const float* mem_k    = (const float*)d_in[6];
    const void*  vmask    = d_in[7];
    const float* mem_v    = (const float*)d_in[8];
    const float* W_ih     = (const float*)d_in[9];
    const float* W_hh     = (const float*)d_in[10];
    const float* b_ih     = (const float*)d_in[11];
    const float* b_hh     = (const float*)d_in[12];
    const float* mlp_W1   = (const float*)d_in[13];
    const float* mlp_b1   = (const float*)d_in[14];
    const float* mlp_W2   = (const float*)d_in[15];
    const float* mlp_b2   = (const float*)d_in[16];
    const float* emb      = (const float*)d_in[17];
    const float* dense_W  = (const float*)d_in[18];
    const float* dense_b  = (const float*)d_in[19];
    const float* read_W   = (const float*)d_in[20];
    const float* read_b   = (const float*)d_in[21];
    float* d_out = (float*)d_out_v;
    float* ws = (float*)d_ws;

    float* h       = ws;            // 32768
    float* c       = ws + 32768;    // 32768
    float* x       = ws + 65536;    // 24576
    float* g       = ws + 90112;    // 131072
    float* hid     = ws + 221184;   // 32768
    float* lmask   = ws + 253952;   // 262144
    float* sent    = ws + 516096;   // 16384
    float* pad     = ws + 532480;   // 8192
    float* key_run = ws + 540672;   // 32768
    float* val_sim = ws + 573440;   // 32768
    float* normk   = ws + 606208;   // 32768
    float* normv   = ws + 638976;   // 32768
    float* rowmax  = ws + 671744;   // 32768
    int*   nidbuf  = (int*)(ws + 704512);  // 32 ints (pad to 64)
    float* mqg     = ws + 704576;   // 8192
    float* qbuf    = ws + 712768;   // 16384
    float* part    = ws + 729152;   // 32*8*516 = 132096
    // total ≈ 861248 floats ≈ 3.3 MB

    k_init<<<1024, 256, 0, stream>>>(hidden, cell, enc, encmask, h, c, x, lmask, sent, pad, key_run, val_sim);
    k_norms<<<256, 256, 0, stream>>>(mem_k, mem_v, normk, normv);
    k_rowmax_mfma<<<dim3(8, 32), 256, 0, stream>>>(mem_k, mem_v, normk, normv, rowmax);

    for (int t = 0; t < T_; ++t) {
        // gates = x@W_ih^T + h@W_hh^T + b_ih + b_hh   (K = 768 + 1024)
        k_gemm2<<<G4_ / 16, 256, 0, stream>>>(x, W_ih, EIN_, h, W_hh, HD_,
                                              b_ih, b_hh, nullptr, 0, g, G4_, 0, nullptr);
        k_lstm<<<128, 256, 0, stream>>>(g, h, c);
        // hid = relu(h@W1^T + b1)
        k_gemm2<<<HD_ / 16, 256, 0, stream>>>(h, mlp_W1, HD_, nullptr, nullptr, 0,
                                              mlp_b1, nullptr, nullptr, 0, hid, HD_, 1, nullptr);
        // logits = hid@W2^T + b2 + lmask  -> d_out[:, t, :]
        k_gemm2<<<N_ / 16, 256, 0, stream>>>(hid, mlp_W2, HD_, nullptr, nullptr, 0,
                                             mlp_b2, nullptr, lmask, N_,
                                             d_out + (size_t)t * N_, (long long)T_ * N_, 0, nullptr);
        k_argmax<<<B_, 256, 0, stream>>>(d_out, t, nidbuf, lmask);
        // q = lab@dense_W^T + dense_b   (lab gathered from emb via nid)
        k_gemm2<<<HE_ / 16, 256, 0, stream>>>(emb, dense_W, ED_, nullptr, nullptr, 0,
                                              dense_b, nullptr, nullptr, 0, qbuf, HE_, 0, nidbuf);
        k_attn1<<<dim3(8, B_), 256, 0, stream>>>(qbuf, enc, pad, part);
        k_attn2<<<B_, 256, 0, stream>>>(part, sent, nidbuf, emb, x);
        // mq = x@read_W^T + read_b
        k_gemm2<<<MD_ / 16, 256, 0, stream>>>(x, read_W, EIN_, nullptr, nullptr, 0,
                                              read_b, nullptr, nullptr, 0, mqg, MD_, 0, nullptr);
        k_ksim<<<dim3(16, B_), 256, 0, stream>>>(mqg, mem_k, normk, key_run);
    }

    k_keyfinal<<<128, 256, 0, stream>>>(key_run, kmask, d_out);
    k_val<<<128, 256, 0, stream>>>(rowmax, mem_k, mem_v, normk, normv, key_run, val_sim);
    k_valout<<<128, 256, 0, stream>>>(val_sim, vmask, d_out);
}